// Round 1
// baseline (376.431 us; speedup 1.0000x reference)
//
#include <hip/hip_runtime.h>

// ---------------- problem constants ----------------
#define T_ 8
#define N_ 256
#define C_ 1024
#define H_ 16
#define D_ 64
#define U_ 2056      // fused tokens per batch = T*(N+1)
#define UPAD_ 2112   // 33*64
#define MROWS_ 4112  // B*U
#define MPAD_ 4224   // 33*128
#define IMG_OUT_ELEMS 4194304  // 2*8*256*1024

typedef __attribute__((ext_vector_type(4))) float f32x4;
typedef __attribute__((ext_vector_type(8))) short s16x8;
typedef __attribute__((ext_vector_type(4))) short s16x4;

__device__ __forceinline__ short f2bf(float f) {
  union { float f; unsigned u; } a; a.f = f;
  unsigned u = a.u;
  return (short)((u + 0x7fffu + ((u >> 16) & 1u)) >> 16);
}

#define ASYNC_COPY16(gp, lp)                                                   \
  __builtin_amdgcn_global_load_lds((const __attribute__((address_space(1))) void*)(gp), \
                                   (__attribute__((address_space(3))) void*)(lp), 16, 0, 0)

// ---------------- workspace offsets (bytes) ----------------
constexpr size_t OFF_XB     = 0;                         // 4224*1024*2
constexpr size_t OFF_WQKVT  = OFF_XB + 8650752;          // 3072*1024*2
constexpr size_t OFF_WPROJT = OFF_WQKVT + 6291456;       // 1024*1024*2
constexpr size_t OFF_Q      = OFF_WPROJT + 2097152;      // 32*2056*64*2
constexpr size_t OFF_K      = OFF_Q + 8421376;           // 32*2112*64*2
constexpr size_t OFF_V      = OFF_K + 8650752;           // 32*2112*64*2
constexpr size_t OFF_VT     = OFF_V + 8650752;           // 32*64*2112*2
constexpr size_t OFF_X      = OFF_VT + 8650752;          // 4224*1024*2
// total ~60 MB

// ---------------- pack img+cam -> fused-order bf16 X ----------------
__global__ __launch_bounds__(256) void pack_x_kernel(const float* __restrict__ img,
                                                     const float* __restrict__ cam,
                                                     short* __restrict__ Xb) {
  int gt = blockIdx.x * 256 + threadIdx.x;
  int e = gt << 2;                      // 4 floats per thread, exact cover of 4112*1024
  int row = e >> 10, col = e & 1023;
  int b = row / U_, u = row % U_, t = u / 257, jj = u % 257;
  const float* src = jj ? (img + ((size_t)((b * 8 + t) * 256 + (jj - 1)) << 10))
                        : (cam + ((size_t)(b * 8 + t) << 10));
  float4 f = *(const float4*)(src + col);
  s16x4 o;
  o[0] = f2bf(f.x); o[1] = f2bf(f.y); o[2] = f2bf(f.z); o[3] = f2bf(f.w);
  *(s16x4*)(Xb + ((size_t)row << 10) + col) = o;
}

// ---------------- fp32 [R][Cc] -> bf16 [Cc][R] transpose ----------------
__global__ __launch_bounds__(256) void wt_kernel(const float* __restrict__ in,
                                                 short* __restrict__ out, int R, int Cc) {
  __shared__ float tile[32][33];
  int tx = threadIdx.x & 31, ty = threadIdx.x >> 5;
  int col0 = blockIdx.x << 5, row0 = blockIdx.y << 5;
#pragma unroll
  for (int i = 0; i < 4; i++) {
    int r = ty + i * 8;
    tile[r][tx] = in[(size_t)(row0 + r) * Cc + col0 + tx];
  }
  __syncthreads();
#pragma unroll
  for (int i = 0; i < 4; i++) {
    int r = ty + i * 8;
    out[(size_t)(col0 + r) * R + row0 + tx] = f2bf(tile[tx][r]);
  }
}

// ---------------- bf16 v[bh][2112][64] -> vt[bh][64][2112] ----------------
__global__ __launch_bounds__(256) void vt_kernel(const short* __restrict__ v,
                                                 short* __restrict__ vt) {
  __shared__ __align__(16) short t2[64][65];
  int tid = threadIdx.x;
  int kt = blockIdx.x, bh = blockIdx.y;
#pragma unroll
  for (int i = 0; i < 16; i++) {
    int e = tid + i * 256; int r = e >> 6, c = e & 63;
    t2[r][c] = v[((size_t)bh * UPAD_ + kt * 64 + r) * 64 + c];
  }
  __syncthreads();
#pragma unroll
  for (int i = 0; i < 16; i++) {
    int e = tid + i * 256; int d = e >> 6, c = e & 63;
    vt[((size_t)bh * 64 + d) * UPAD_ + kt * 64 + c] = t2[c][d];
  }
}

// ---------------- 128x128 bf16 GEMM, Bt is [N][K] row-major ----------------
// EPI 0: QKV epilogue (RoPE + q/k/v scatter).  EPI 1: proj epilogue (bias + out scatter).
template <int EPI>
__global__ __launch_bounds__(256) void gemm_kernel(
    const short* __restrict__ A, const short* __restrict__ Bt,
    const float* __restrict__ cosi, const float* __restrict__ sini,
    const float* __restrict__ cosc, const float* __restrict__ sinc,
    short* __restrict__ qb, short* __restrict__ kb, short* __restrict__ vb,
    const float* __restrict__ bias, float* __restrict__ outp) {
  constexpr int K = 1024;
  __shared__ __align__(16) short As[128 * 32];
  __shared__ __align__(16) short Bs[128 * 32];
  const int tid = threadIdx.x, w = tid >> 6, lane = tid & 63;
  const int l16 = lane & 15, quad = lane >> 4;
  const int bn = blockIdx.x, bm = blockIdx.y;
  const f32x4 zero = {0.f, 0.f, 0.f, 0.f};
  f32x4 acc[4][4];
#pragma unroll
  for (int i = 0; i < 4; i++)
#pragma unroll
    for (int j = 0; j < 4; j++) acc[i][j] = zero;

  const int mb = (w >> 1) << 6, nb = (w & 1) << 6;

  for (int kb0 = 0; kb0 < K; kb0 += 32) {
    __syncthreads();
#pragma unroll
    for (int i = 0; i < 2; i++) {
      int row = (w << 5) + (i << 4) + (lane >> 2);
      int cseg = (lane & 3) << 3;
      const short* ga = A + (size_t)(bm * 128 + row) * K + kb0 + cseg;
      char* la = (char*)As + ((w << 5) + (i << 4)) * 64 + lane * 16;
      ASYNC_COPY16(ga, la);
      const short* gb = Bt + (size_t)(bn * 128 + row) * K + kb0 + cseg;
      char* lb = (char*)Bs + ((w << 5) + (i << 4)) * 64 + lane * 16;
      ASYNC_COPY16(gb, lb);
    }
    __syncthreads();
    s16x8 af[4], bf[4];
#pragma unroll
    for (int mi = 0; mi < 4; mi++)
      af[mi] = *(const s16x8*)&As[(mb + mi * 16 + l16) * 32 + quad * 8];
#pragma unroll
    for (int ni = 0; ni < 4; ni++)
      bf[ni] = *(const s16x8*)&Bs[(nb + ni * 16 + l16) * 32 + quad * 8];
#pragma unroll
    for (int mi = 0; mi < 4; mi++)
#pragma unroll
      for (int ni = 0; ni < 4; ni++)
        acc[mi][ni] = __builtin_amdgcn_mfma_f32_16x16x32_bf16(af[mi], bf[ni], acc[mi][ni], 0, 0, 0);
  }

  // epilogue: C/D layout col = lane&15, row = quad*4 + reg
#pragma unroll
  for (int mi = 0; mi < 4; mi++) {
#pragma unroll
    for (int ni = 0; ni < 4; ni++) {
#pragma unroll
      for (int reg = 0; reg < 4; reg++) {
        float val = acc[mi][ni][reg];
        float partner = __shfl_xor(val, 1, 64);  // neighbor column (d^1), same row
        int R = bm * 128 + mb + mi * 16 + quad * 4 + reg;
        int Cg = bn * 128 + nb + ni * 16 + l16;
        int b = R / U_;
        if (b < 2) {
          int u = R % U_, t = u / 257, jj = u % 257;
          if constexpr (EPI == 0) {
            int which = Cg >> 10, hc = Cg & 1023, h = hc >> 6, d = hc & 63;
            int bh = b * 16 + h;
            if (which == 2) {
              vb[((size_t)bh * UPAD_ + u) * 64 + d] = f2bf(val);
            } else {
              const float *ct, *st; int pos;
              if (jj == 0) { ct = cosc; st = sinc; pos = t; }
              else         { ct = cosi; st = sini; pos = u - t - 1; }
              float cv = ct[pos * 64 + d], sv = st[pos * 64 + d];
              float o = val * cv + ((d & 1) ? partner : -partner) * sv;
              if (which == 0) {
                o *= 0.125f;  // fold 1/sqrt(64) into q
                qb[((size_t)bh * U_ + u) * 64 + d] = f2bf(o);
              } else {
                kb[((size_t)bh * UPAD_ + u) * 64 + d] = f2bf(o);
              }
            }
          } else {
            float o = val + bias[Cg];
            if (jj) outp[(size_t)((b * 8 + t) * 256 + jj - 1) * 1024 + Cg] = o;
            else    outp[IMG_OUT_ELEMS + (size_t)(b * 8 + t) * 1024 + Cg] = o;
          }
        }
      }
    }
  }
}

// ---------------- fused flash attention ----------------
// grid: (33 q-tiles, 32 bh). q-tiles 0..31 = img (64 rows), 32 = cam (rows 0..7 real)
__global__ __launch_bounds__(256) void attn_kernel(const short* __restrict__ q,
                                                   const short* __restrict__ k,
                                                   const short* __restrict__ vt,
                                                   short* __restrict__ x) {
  __shared__ __align__(16) short Kt[64][72];
  __shared__ __align__(16) short Vt[64][72];
  __shared__ __align__(16) short Pt[4][16][72];
  const int tid = threadIdx.x, w = tid >> 6, lane = tid & 63;
  const int l16 = lane & 15, quad = lane >> 4;
  const int qt = blockIdx.x, bh = blockIdx.y;
  const int b = bh >> 4, h = bh & 15;
  const bool camq = (qt == 32);

  int u_q;
  if (!camq) { int g = qt * 64 + w * 16 + l16; u_q = g + (g >> 8) + 1; }
  else       { u_q = (l16 & 7) * 257; }
  const short* qp = q + ((size_t)bh * U_ + u_q) * 64;
  s16x8 aq0 = *(const s16x8*)(qp + quad * 8);
  s16x8 aq1 = *(const s16x8*)(qp + 32 + quad * 8);

  const f32x4 zero = {0.f, 0.f, 0.f, 0.f};
  float m_r[4], l_r[4];
  f32x4 o_acc[4];
#pragma unroll
  for (int r = 0; r < 4; r++) { m_r[r] = -3e38f; l_r[r] = 0.f; o_acc[r] = zero; }

  for (int kv0 = 0; kv0 < U_; kv0 += 64) {
    __syncthreads();
    {
      int r = tid >> 2, sg = (tid & 3) << 3;
      const short* kp = k + ((size_t)bh * UPAD_ + kv0 + r) * 64;
      *(s16x8*)&Kt[r][sg]      = *(const s16x8*)(kp + sg);
      *(s16x8*)&Kt[r][32 + sg] = *(const s16x8*)(kp + 32 + sg);
      const short* vp = vt + ((size_t)bh * 64 + r) * UPAD_ + kv0;
      *(s16x8*)&Vt[r][sg]      = *(const s16x8*)(vp + sg);
      *(s16x8*)&Vt[r][32 + sg] = *(const s16x8*)(vp + 32 + sg);
    }
    __syncthreads();

    // S = Q K^T  (q pre-scaled)
    f32x4 s_acc[4];
#pragma unroll
    for (int ni = 0; ni < 4; ni++) {
      s16x8 b0 = *(const s16x8*)&Kt[ni * 16 + l16][quad * 8];
      s16x8 b1 = *(const s16x8*)&Kt[ni * 16 + l16][32 + quad * 8];
      f32x4 z = zero;
      z = __builtin_amdgcn_mfma_f32_16x16x32_bf16(aq0, b0, z, 0, 0, 0);
      z = __builtin_amdgcn_mfma_f32_16x16x32_bf16(aq1, b1, z, 0, 0, 0);
      s_acc[ni] = z;
    }
    // mask: kv tail (>=2056) always; cam rows frame-causal
#pragma unroll
    for (int reg = 0; reg < 4; reg++) {
      int rrow = quad * 4 + reg;
      int limit = camq ? ((rrow & 7) + 1) * 257 : U_;
#pragma unroll
      for (int ni = 0; ni < 4; ni++) {
        int kvg = kv0 + ni * 16 + l16;
        if (kvg >= limit) s_acc[ni][reg] = -1e30f;
      }
    }
    // online softmax (rows live across l16 lanes of each quad)
    float alpha[4];
#pragma unroll
    for (int reg = 0; reg < 4; reg++) {
      float mx = fmaxf(fmaxf(s_acc[0][reg], s_acc[1][reg]),
                       fmaxf(s_acc[2][reg], s_acc[3][reg]));
      mx = fmaxf(mx, __shfl_xor(mx, 1, 64));
      mx = fmaxf(mx, __shfl_xor(mx, 2, 64));
      mx = fmaxf(mx, __shfl_xor(mx, 4, 64));
      mx = fmaxf(mx, __shfl_xor(mx, 8, 64));
      float mnew = fmaxf(m_r[reg], mx);
      alpha[reg] = __expf(m_r[reg] - mnew);
      m_r[reg] = mnew;
      float rs = 0.f;
#pragma unroll
      for (int ni = 0; ni < 4; ni++) {
        float p = __expf(s_acc[ni][reg] - mnew);
        s_acc[ni][reg] = p;
        rs += p;
      }
      rs += __shfl_xor(rs, 1, 64);
      rs += __shfl_xor(rs, 2, 64);
      rs += __shfl_xor(rs, 4, 64);
      rs += __shfl_xor(rs, 8, 64);
      l_r[reg] = l_r[reg] * alpha[reg] + rs;
    }
#pragma unroll
    for (int ni = 0; ni < 4; ni++)
#pragma unroll
      for (int reg = 0; reg < 4; reg++) o_acc[ni][reg] *= alpha[reg];

    // P: C-layout -> LDS -> A-layout (per-wave region, no barrier needed)
#pragma unroll
    for (int ni = 0; ni < 4; ni++)
#pragma unroll
      for (int reg = 0; reg < 4; reg++)
        Pt[w][quad * 4 + reg][ni * 16 + l16] = f2bf(s_acc[ni][reg]);

    // O += P V
#pragma unroll
    for (int ks = 0; ks < 2; ks++) {
      s16x8 ap = *(const s16x8*)&Pt[w][l16][ks * 32 + quad * 8];
#pragma unroll
      for (int ni = 0; ni < 4; ni++) {
        s16x8 bv = *(const s16x8*)&Vt[ni * 16 + l16][ks * 32 + quad * 8];
        o_acc[ni] = __builtin_amdgcn_mfma_f32_16x16x32_bf16(ap, bv, o_acc[ni], 0, 0, 0);
      }
    }
  }

  // write x[b*2056+u][h*64+d] bf16
#pragma unroll
  for (int reg = 0; reg < 4; reg++) {
    int rrow = quad * 4 + reg;
    float inv = 1.f / l_r[reg];
    int u_o; bool wr = true;
    if (!camq) { int g = qt * 64 + w * 16 + rrow; u_o = g + (g >> 8) + 1; }
    else       { u_o = (rrow & 7) * 257; wr = (w == 0) && (rrow < 8); }
    if (wr) {
#pragma unroll
      for (int ni = 0; ni < 4; ni++)
        x[((size_t)(b * U_ + u_o)) * 1024 + h * 64 + ni * 16 + l16] = f2bf(o_acc[ni][reg] * inv);
    }
  }
}

// ---------------- launch ----------------
extern "C" void kernel_launch(void* const* d_in, const int* in_sizes, int n_in,
                              void* d_out, int out_size, void* d_ws, size_t ws_size,
                              hipStream_t stream) {
  const float* img   = (const float*)d_in[0];
  const float* cam   = (const float*)d_in[1];
  const float* wqkv  = (const float*)d_in[2];
  const float* wproj = (const float*)d_in[3];
  const float* bias  = (const float*)d_in[4];
  const float* cosi  = (const float*)d_in[5];
  const float* sini  = (const float*)d_in[6];
  const float* cosc  = (const float*)d_in[7];
  const float* sinc  = (const float*)d_in[8];
  float* outp = (float*)d_out;

  char* ws = (char*)d_ws;
  short* Xb     = (short*)(ws + OFF_XB);
  short* Wqkvt  = (short*)(ws + OFF_WQKVT);
  short* Wprojt = (short*)(ws + OFF_WPROJT);
  short* qb     = (short*)(ws + OFF_Q);
  short* kb     = (short*)(ws + OFF_K);
  short* vb     = (short*)(ws + OFF_V);
  short* vtb    = (short*)(ws + OFF_VT);
  short* xb     = (short*)(ws + OFF_X);

  pack_x_kernel<<<4112, 256, 0, stream>>>(img, cam, Xb);
  wt_kernel<<<dim3(96, 32), 256, 0, stream>>>(wqkv, Wqkvt, 1024, 3072);
  wt_kernel<<<dim3(32, 32), 256, 0, stream>>>(wproj, Wprojt, 1024, 1024);
  gemm_kernel<0><<<dim3(24, 33), 256, 0, stream>>>(Xb, Wqkvt, cosi, sini, cosc, sinc,
                                                   qb, kb, vb, nullptr, nullptr);
  vt_kernel<<<dim3(33, 32), 256, 0, stream>>>(vb, vtb);
  attn_kernel<<<dim3(33, 32), 256, 0, stream>>>(qb, kb, vtb, xb);
  gemm_kernel<1><<<dim3(8, 33), 256, 0, stream>>>(xb, Wprojt, nullptr, nullptr, nullptr, nullptr,
                                                  nullptr, nullptr, nullptr, bias, outp);
}